// Round 3
// baseline (174.277 us; speedup 1.0000x reference)
//
#include <hip/hip_runtime.h>

#define NB 512
#define NT 512
#define NL 64
#define L2E 1.4426950408889634f   // log2(e)
#define LN2 0.6931471805599453f   // ln(2)

__global__ void zero_out_kernel(float* out) { *out = 0.0f; }

// R13: f32 state + row_ror DPP-gathered f32 FMAs + every-4-step rescale.
// R12 post-mortem: at 1 wave/SIMD the step is LATENCY-bound on a serial
// dependent-VALU chain (825 cy/step vs ~150 issue); the f16 state forced
// cvt+pack+5-level butterfly AND a per-step readfirstlane rescale (f16
// range 2^±15 < per-step growth 2^13). Fixes:
//  - state stays f32; gather is 16 independent v_mov_dpp row_ror:k off the
//    SAME register (no serial butterfly); 64 independent v_fmac_f32 in 8
//    acc chains of depth 8. row_ror direction is PROBED at prologue (each
//    lane rotates its own column id and indexes trans with the observed
//    permutation) -- correct for either rotation direction.
//  - rescale (readfirstlane->SALU->VALU round trip) every 4 steps only;
//    worst-case growth 2^13.4/step * 4 = 2^54 << f32 range. Exact powers
//    of 2, integer G bookkeeping unchanged.
//  - reduce = R12's verified direction-proof permlane16/32 self-swap sums.
// Everything else (mask ballots, em prefetch ring, path score, fwd/bwd T/2
// split, junction) kept verbatim.

template <int K>
__device__ __forceinline__ unsigned roru(unsigned x) {
  if constexpr (K == 0) return x;
  else
    return (unsigned)__builtin_amdgcn_mov_dpp((int)x, 0x120 + K, 0xF, 0xF, true);
}
template <int K>
__device__ __forceinline__ float rorf(float x) {
  return __uint_as_float(roru<K>(__float_as_uint(x)));
}

__device__ __forceinline__ float pairsum16(float x) {
#if __has_builtin(__builtin_amdgcn_permlane16_swap)
  unsigned xu = __float_as_uint(x);
  auto rp = __builtin_amdgcn_permlane16_swap(xu, xu, false, false);
  return __uint_as_float(rp[0]) + __uint_as_float(rp[1]);
#else
  return x + __shfl_xor(x, 16, 64);
#endif
}
__device__ __forceinline__ float pairsum32(float x) {
#if __has_builtin(__builtin_amdgcn_permlane32_swap)
  unsigned xu = __float_as_uint(x);
  auto rp = __builtin_amdgcn_permlane32_swap(xu, xu, false, false);
  return __uint_as_float(rp[0]) + __uint_as_float(rp[1]);
#else
  return x + __shfl_xor(x, 32, 64);
#endif
}

// y_out(16q+c) partials over input block r, then cross-r reduce; select q==r.
__device__ __forceinline__ float matvec64f(float s, const float (&ep)[4][16],
                                           int r) {
  float A0 = 0.f, A1 = 0.f, A2 = 0.f, A3 = 0.f;
  float B0 = 0.f, B1 = 0.f, B2 = 0.f, B3 = 0.f;
#define MAC2(K0, K1)                                   \
  {                                                    \
    float ta = rorf<K0>(s), tb = rorf<K1>(s);          \
    A0 = fmaf(ta, ep[0][K0], A0);                      \
    B0 = fmaf(tb, ep[0][K1], B0);                      \
    A1 = fmaf(ta, ep[1][K0], A1);                      \
    B1 = fmaf(tb, ep[1][K1], B1);                      \
    A2 = fmaf(ta, ep[2][K0], A2);                      \
    B2 = fmaf(tb, ep[2][K1], B2);                      \
    A3 = fmaf(ta, ep[3][K0], A3);                      \
    B3 = fmaf(tb, ep[3][K1], B3);                      \
  }
  MAC2(0, 1) MAC2(2, 3) MAC2(4, 5) MAC2(6, 7)
  MAC2(8, 9) MAC2(10, 11) MAC2(12, 13) MAC2(14, 15)
#undef MAC2
  float F0 = pairsum32(pairsum16(A0 + B0));
  float F1 = pairsum32(pairsum16(A1 + B1));
  float F2 = pairsum32(pairsum16(A2 + B2));
  float F3 = pairsum32(pairsum16(A3 + B3));
  float ya = (r & 1) ? F1 : F0;
  float yb = (r & 1) ? F3 : F2;
  return (r & 2) ? yb : ya;
}

__device__ __forceinline__ void rescale4(float& s, int& G) {
  unsigned e0 =
      (__builtin_amdgcn_readfirstlane(__float_as_uint(s)) >> 23) & 0xffu;
  s *= __uint_as_float((254u - e0) << 23);  // 2^(127-e0), exact
  G += (int)e0 - 127;
}

__global__
__attribute__((amdgpu_flat_work_group_size(128, 128), amdgpu_waves_per_eu(1, 1)))
void crf_nll_kernel(
    const float* __restrict__ emission,     // B,T,L
    const int*   __restrict__ target,       // B,T
    const float* __restrict__ mask,         // B,T
    const float* __restrict__ start_trans,  // L
    const float* __restrict__ trans,        // L,L
    const float* __restrict__ end_trans,    // L
    float* __restrict__ out)
{
  const int b = blockIdx.x;
  const int tid = threadIdx.x;
  const int wv = tid >> 6;            // 0 = forward, 1 = backward
  const int j = tid & 63;
  const int r = j >> 4;
  const int c = j & 15;

  const float* em_b = emission + (size_t)b * NT * NL;
  const float* mk_b = mask + (size_t)b * NT;
  const int*   tg_b = target + (size_t)b * NT;

  __shared__ float fF[NL], fB[NL];
  __shared__ float psS[2];
  __shared__ int   GS[2];

  // ---- probe the actual row_ror permutation: pi[k] = source column of
  // ---- lane (r,c) under rorf<k>. Direction-proof by construction.
  int pi[16];
  pi[0] = c;
#define PRB(K) pi[K] = (int)roru<K>((unsigned)c);
  PRB(1) PRB(2) PRB(3) PRB(4) PRB(5) PRB(6) PRB(7) PRB(8)
  PRB(9) PRB(10) PRB(11) PRB(12) PRB(13) PRB(14) PRB(15)
#undef PRB

  // ------- path score: wave wv covers chunks [4wv, 4wv+4) = its T half -----
  float ps = 0.0f;
  #pragma unroll
  for (int cc = 4 * wv; cc < 4 * wv + 4; ++cc) {
    int t = cc * 64 + j;
    int cur = tg_b[t];
    float m  = mk_b[t];
    float mn = (t + 1 < NT) ? mk_b[t + 1] : 0.0f;
    if (t == 0) {
      ps += start_trans[cur] + em_b[cur];
    } else {
      int prev = tg_b[t - 1];
      if (m > 0.5f)
        ps += trans[prev * NL + cur] + em_b[(size_t)t * NL + cur];
      if (m - mn > 0.5f)                 // end_mask = m_t & !m_{t+1}
        ps += end_trans[cur];
    }
  }
  #pragma unroll
  for (int off = 32; off; off >>= 1) ps += __shfl_down(ps, off, 64);

  const float endt = __builtin_amdgcn_exp2f(L2E * end_trans[j]);

  int G = 0;          // exact integer scale deficit (log2 units): true = s*2^G
  float s;

  if (wv == 0) {
    // ======================= FORWARD: t = 0..255 ===========================
    // y = E^T s: ep[q][k] = exp(trans[16r + pi[k]][16q + c])
    float ep[4][16];
    #pragma unroll
    for (int q = 0; q < 4; ++q) {
      const int col = 16 * q + c;
      #pragma unroll
      for (int k = 0; k < 16; ++k)
        ep[q][k] = __builtin_amdgcn_exp2f(L2E * trans[(16 * r + pi[k]) * NL + col]);
    }
    s = __builtin_amdgcn_exp2f(L2E * (start_trans[j] + em_b[j]));  // t=0

    float pf[8];
    #pragma unroll
    for (int u = 0; u < 8; ++u) pf[u] = L2E * em_b[(size_t)u * NL + j];

    #pragma unroll 1
    for (int cc = 0; cc < 4; ++cc) {
      const int tb = cc * 64;
      float ml = mk_b[tb + j];
      int nidx = tb + j + 1;
      float mnext = (nidx < NT) ? mk_b[nidx] : 0.0f;
      unsigned long long cm = __ballot(ml > 0.5f);
      unsigned long long ce = __ballot(ml - mnext > 0.5f);
      if (cc == 0) { cm &= ~1ull; ce &= ~1ull; }  // t=0 handled by init

      #pragma unroll 1
      for (int i8 = 0; i8 < 64; i8 += 8) {
        #pragma unroll
        for (int u = 0; u < 8; ++u) {
          const int i = i8 + u;
          // off-chain: eem (endt folded), prefetch t+8
          float eemu = __builtin_amdgcn_exp2f(pf[u]);
          eemu = ((ce >> i) & 1) ? eemu * endt : eemu;
          int tp = tb + i + 8; if (tp > NT - 1) tp = NT - 1;
          pf[u] = L2E * em_b[(size_t)tp * NL + j];
          // chain: DPP-fused f32 matvec -> eem mul -> select
          float sm = matvec64f(s, ep, r) * eemu;
          s = ((cm >> i) & 1) ? sm : s;
          if ((u & 3) == 3) rescale4(s, G);      // every 4th step
        }
      }
    }
  } else {
    // ======================= BACKWARD: t = 511..256 ========================
    // v' = E (v o w): epb[q][k] = exp(trans[16q + c][16r + pi[k]])
    float ep[4][16];
    #pragma unroll
    for (int q = 0; q < 4; ++q) {
      const int rowi = 16 * q + c;
      #pragma unroll
      for (int k = 0; k < 16; ++k)
        ep[q][k] = __builtin_amdgcn_exp2f(L2E * trans[rowi * NL + 16 * r + pi[k]]);
    }
    s = 1.0f;                                   // v^T = 1^T

    float pf[8];                                 // pf[t&7] = l2e*em[t][j]
    #pragma unroll
    for (int u = 0; u < 8; ++u) pf[u] = L2E * em_b[(size_t)(504 + u) * NL + j];

    #pragma unroll 1
    for (int cc = 7; cc >= 4; --cc) {
      const int tb = cc * 64;
      float ml = mk_b[tb + j];
      int nidx = tb + j + 1;
      float mnext = (nidx < NT) ? mk_b[nidx] : 0.0f;
      unsigned long long cm = __ballot(ml > 0.5f);
      unsigned long long ce = __ballot(ml - mnext > 0.5f);

      #pragma unroll 1
      for (int i8 = 56; i8 >= 0; i8 -= 8) {
        #pragma unroll
        for (int u = 7; u >= 0; --u) {
          const int i = i8 + u;
          const int t = tb + i;                  // t & 7 == u
          // off-chain: wmul = eem^{m} * endt^{e}, prefetch t-8
          float eemu = __builtin_amdgcn_exp2f(pf[u]);
          float wmul = ((cm >> i) & 1) ? eemu : 1.0f;
          wmul = ((ce >> i) & 1) ? wmul * endt : wmul;
          int tp = t - 8; if (tp < 0) tp = 0;
          pf[u] = L2E * em_b[(size_t)tp * NL + j];
          // chain: w = s*wmul -> matvec (uniform branch) -> rescale
          float w = s * wmul;
          if ((cm >> i) & 1) s = matvec64f(w, ep, r);
          else               s = w;              // A_t = I (masked-out step)
          if ((u & 3) == 0) rescale4(s, G);      // every 4th step
        }
      }
    }
  }

  // ---------------- junction: norm = log(v . q) + (Gf+Gb)*ln2 ---------------
  if (wv == 0) { fF[j] = s; if (j == 0) { psS[0] = ps; GS[0] = G; } }
  else         { fB[j] = s; if (j == 0) { psS[1] = ps; GS[1] = G; } }
  __syncthreads();
  if (wv == 0) {
    float prod = s * fB[j];
    #pragma unroll
    for (int off = 32; off; off >>= 1) prod += __shfl_xor(prod, off, 64);
    if (j == 0) {
      float norm = (__builtin_amdgcn_logf(prod) + (float)(GS[0] + GS[1])) * LN2;
      atomicAdd(out, (norm - psS[0] - psS[1]) * (1.0f / (float)NB));
    }
  }
}

extern "C" void kernel_launch(void* const* d_in, const int* in_sizes, int n_in,
                              void* d_out, int out_size, void* d_ws, size_t ws_size,
                              hipStream_t stream) {
  const float* emission    = (const float*)d_in[0];
  const int*   target      = (const int*)  d_in[1];
  const float* mask        = (const float*)d_in[2];
  const float* start_trans = (const float*)d_in[3];
  const float* trans       = (const float*)d_in[4];
  const float* end_trans   = (const float*)d_in[5];
  float* out = (float*)d_out;

  zero_out_kernel<<<1, 1, 0, stream>>>(out);
  crf_nll_kernel<<<NB, 128, 0, stream>>>(emission, target, mask, start_trans,
                                         trans, end_trans, out);
}